// Round 3
// baseline (2433.629 us; speedup 1.0000x reference)
//
#include <hip/hip_runtime.h>

#define F 128
#define RB 64          // rows per bucket
#define RB_SHIFT 6
#define SCH 16384      // edges per partition block
#define COL_BITS 17
#define COL_MASK 0x1FFFF

// ---- kernel 1: per-bucket histogram (LDS-aggregated) ----
__global__ void hist_kernel(const int* __restrict__ rows, int* __restrict__ counts,
                            int n_edges, int nb) {
    extern __shared__ int h[];
    int t = threadIdx.x;
    for (int i = t; i < nb; i += blockDim.x) h[i] = 0;
    __syncthreads();
    int stride = gridDim.x * blockDim.x;
    for (int e = blockIdx.x * blockDim.x + t; e < n_edges; e += stride)
        atomicAdd(&h[rows[e] >> RB_SHIFT], 1);
    __syncthreads();
    for (int i = t; i < nb; i += blockDim.x) {
        int c = h[i];
        if (c) atomicAdd(&counts[i], c);
    }
}

// ---- kernel 2: single-block exclusive scan over nb buckets ----
__global__ void scan_kernel(const int* __restrict__ counts, int* __restrict__ offs,
                            int* __restrict__ cursor, int nb) {
    __shared__ int lds[1024];
    int t = threadIdx.x;
    int per = (nb + 1023) / 1024;
    int base = t * per;
    int s = 0;
    for (int i = 0; i < per; i++)
        if (base + i < nb) s += counts[base + i];
    lds[t] = s;
    __syncthreads();
    for (int off = 1; off < 1024; off <<= 1) {
        int add = (t >= off) ? lds[t - off] : 0;
        __syncthreads();
        lds[t] += add;
        __syncthreads();
    }
    int excl = lds[t] - s;
    for (int i = 0; i < per; i++) {
        if (base + i < nb) {
            offs[base + i] = excl;
            cursor[base + i] = excl;
            excl += counts[base + i];
        }
    }
}

// ---- kernel 3: block-aggregated partition into bucket regions ----
__global__ void partition_kernel(const int* __restrict__ rows, const int* __restrict__ cols,
                                 const float* __restrict__ vals, int* __restrict__ gcursor,
                                 int2* __restrict__ epk, int n_edges, int nb) {
    extern __shared__ int lds[];
    int* hist = lds;
    int* cur = lds + nb;
    int t = threadIdx.x;
    int e0 = blockIdx.x * SCH;
    int e1 = min(e0 + SCH, n_edges);

    for (int i = t; i < nb; i += blockDim.x) hist[i] = 0;
    __syncthreads();
    for (int e = e0 + t; e < e1; e += blockDim.x)
        atomicAdd(&hist[rows[e] >> RB_SHIFT], 1);
    __syncthreads();
    for (int i = t; i < nb; i += blockDim.x) {
        int c = hist[i];
        cur[i] = c ? atomicAdd(&gcursor[i], c) : 0;
    }
    __syncthreads();
    for (int e = e0 + t; e < e1; e += blockDim.x) {
        int r = rows[e];
        int b = r >> RB_SHIFT;
        int p = atomicAdd(&cur[b], 1);
        epk[p] = make_int2(cols[e] | ((r & (RB - 1)) << COL_BITS),
                           __float_as_int(vals[e]));
    }
}

// ---- kernel 4: per-bucket LDS accumulation + bias + coalesced write ----
__global__ __launch_bounds__(256) void accum_kernel(
    const int* __restrict__ offs, const int* __restrict__ counts,
    const int2* __restrict__ epk, const float* __restrict__ weight,
    const float* __restrict__ bias, float* __restrict__ out, int n_nodes) {
    __shared__ float acc[RB * F];  // 32 KB
    int b = blockIdx.x;
    int t = threadIdx.x;
    for (int i = t; i < RB * F / 4; i += blockDim.x)
        ((float4*)acc)[i] = make_float4(0.f, 0.f, 0.f, 0.f);
    __syncthreads();

    int s = offs[b];
    int end = s + counts[b];
    int wave = t >> 6, lane = t & 63, nw = blockDim.x >> 6;
    const float2* w2 = (const float2*)weight;

    int e = s + wave;
    // 4-deep ILP: independent gathers in flight
    for (; e + 3 * nw < end; e += 4 * nw) {
        int2 p0 = epk[e], p1 = epk[e + nw], p2 = epk[e + 2 * nw], p3 = epk[e + 3 * nw];
        float2 wa = w2[(size_t)(p0.x & COL_MASK) * 64 + lane];
        float2 wb = w2[(size_t)(p1.x & COL_MASK) * 64 + lane];
        float2 wc = w2[(size_t)(p2.x & COL_MASK) * 64 + lane];
        float2 wd = w2[(size_t)(p3.x & COL_MASK) * 64 + lane];
        float v0 = __int_as_float(p0.y), v1 = __int_as_float(p1.y);
        float v2 = __int_as_float(p2.y), v3 = __int_as_float(p3.y);
        int r0 = (p0.x >> COL_BITS) * F + 2 * lane;
        int r1 = (p1.x >> COL_BITS) * F + 2 * lane;
        int r2 = (p2.x >> COL_BITS) * F + 2 * lane;
        int r3 = (p3.x >> COL_BITS) * F + 2 * lane;
        atomicAdd(&acc[r0], v0 * wa.x);
        atomicAdd(&acc[r0 + 1], v0 * wa.y);
        atomicAdd(&acc[r1], v1 * wb.x);
        atomicAdd(&acc[r1 + 1], v1 * wb.y);
        atomicAdd(&acc[r2], v2 * wc.x);
        atomicAdd(&acc[r2 + 1], v2 * wc.y);
        atomicAdd(&acc[r3], v3 * wd.x);
        atomicAdd(&acc[r3 + 1], v3 * wd.y);
    }
    for (; e < end; e += nw) {
        int2 pk = epk[e];
        float2 w = w2[(size_t)(pk.x & COL_MASK) * 64 + lane];
        float v = __int_as_float(pk.y);
        int rl = (pk.x >> COL_BITS) * F + 2 * lane;
        atomicAdd(&acc[rl], v * w.x);
        atomicAdd(&acc[rl + 1], v * w.y);
    }
    __syncthreads();

    int row0 = b * RB;
    const float4* b4 = (const float4*)bias;
    for (int i = t; i < RB * F / 4; i += blockDim.x) {
        int rl = i >> 5;  // 32 float4 per row
        int gr = row0 + rl;
        if (gr < n_nodes) {
            float4 a = ((float4*)acc)[i];
            float4 bb = b4[i & 31];
            a.x += bb.x; a.y += bb.y; a.z += bb.z; a.w += bb.w;
            ((float4*)out)[(size_t)gr * 32 + (i & 31)] = a;
        }
    }
}

// ---------------- fallback: atomic path ----------------
__global__ void init_out_kernel(float* __restrict__ out, const float* __restrict__ bias,
                                int n_nodes) {
    const float4* b4 = (const float4*)bias;
    float4* o4 = (float4*)out;
    int total = n_nodes * (F / 4);
    for (int i = blockIdx.x * blockDim.x + threadIdx.x; i < total;
         i += gridDim.x * blockDim.x)
        o4[i] = b4[i & (F / 4 - 1)];
}

__global__ void edge_scatter_kernel(const int* __restrict__ rows,
                                    const int* __restrict__ cols,
                                    const float* __restrict__ vals,
                                    const float* __restrict__ weight,
                                    float* __restrict__ out, int n_edges) {
    int e = (blockIdx.x * blockDim.x + threadIdx.x) >> 6;
    if (e >= n_edges) return;
    int lane = threadIdx.x & 63;
    float2 w = ((const float2*)(weight + (size_t)cols[e] * F))[lane];
    float val = vals[e];
    float* o = out + (size_t)rows[e] * F + lane * 2;
    unsafeAtomicAdd(o, val * w.x);
    unsafeAtomicAdd(o + 1, val * w.y);
}

extern "C" void kernel_launch(void* const* d_in, const int* in_sizes, int n_in,
                              void* d_out, int out_size, void* d_ws, size_t ws_size,
                              hipStream_t stream) {
    const int*   rows   = (const int*)d_in[0];
    const int*   cols   = (const int*)d_in[1];
    const float* vals   = (const float*)d_in[2];
    const float* weight = (const float*)d_in[3];
    const float* bias   = (const float*)d_in[4];
    float* out = (float*)d_out;

    int n_edges = in_sizes[0];
    int n_nodes = out_size / F;
    int nb = (n_nodes + RB - 1) / RB;

    size_t need = ((size_t)3 * nb + 2 * (size_t)n_edges) * 4;

    if (ws_size < need || nb > 1024 * 64) {
        init_out_kernel<<<2048, 256, 0, stream>>>(out, bias, n_nodes);
        int grid = (n_edges + 3) / 4;
        edge_scatter_kernel<<<grid, 256, 0, stream>>>(rows, cols, vals, weight, out,
                                                      n_edges);
        return;
    }

    int* counts = (int*)d_ws;
    int* offs   = counts + nb;
    int* cursor = offs + nb;
    int2* epk   = (int2*)(cursor + nb);

    hipMemsetAsync(counts, 0, (size_t)nb * 4, stream);
    hist_kernel<<<512, 256, nb * 4, stream>>>(rows, counts, n_edges, nb);
    scan_kernel<<<1, 1024, 0, stream>>>(counts, offs, cursor, nb);
    int pgrid = (n_edges + SCH - 1) / SCH;
    partition_kernel<<<pgrid, 256, 2 * nb * 4, stream>>>(rows, cols, vals, cursor, epk,
                                                         n_edges, nb);
    accum_kernel<<<nb, 256, 0, stream>>>(offs, counts, epk, weight, bias, out, n_nodes);
}

// Round 4
// 452.597 us; speedup vs baseline: 5.3770x; 5.3770x over previous
//
#include <hip/hip_runtime.h>

#define F 128
#define RB 64
#define RB_SHIFT 6
#define SCH 16384
#define COL_BITS 17
#define COL_MASK 0x1FFFF
#define SCAN_CHUNK 512
#define SCAN_THREADS 256
#define LDSCAP 4096

// ---- per-row histogram (global atomics, counters L2-resident) ----
__global__ void hist_kernel(const int* __restrict__ rows, int* __restrict__ counts,
                            int n_edges) {
    int stride = gridDim.x * blockDim.x;
    for (int i = blockIdx.x * blockDim.x + threadIdx.x; i < n_edges; i += stride)
        atomicAdd(&counts[rows[i]], 1);
}

// ---- 3-kernel exact scan over n_nodes row counts ----
__global__ void blocksum_kernel(const int* __restrict__ counts, int* __restrict__ partial,
                                int n) {
    __shared__ int lds[SCAN_THREADS];
    int t = threadIdx.x;
    int i0 = blockIdx.x * SCAN_CHUNK + t * 2;
    int s = 0;
    if (i0 < n) s += counts[i0];
    if (i0 + 1 < n) s += counts[i0 + 1];
    lds[t] = s;
    __syncthreads();
    for (int off = SCAN_THREADS / 2; off > 0; off >>= 1) {
        if (t < off) lds[t] += lds[t + off];
        __syncthreads();
    }
    if (t == 0) partial[blockIdx.x] = lds[0];
}

__global__ void scanpartial_kernel(const int* __restrict__ partial,
                                   int* __restrict__ partialscan, int nbs) {
    __shared__ int lds[SCAN_THREADS];
    int t = threadIdx.x;
    int v = (t < nbs) ? partial[t] : 0;
    lds[t] = v;
    __syncthreads();
    for (int off = 1; off < SCAN_THREADS; off <<= 1) {
        int add = (t >= off) ? lds[t - off] : 0;
        __syncthreads();
        lds[t] += add;
        __syncthreads();
    }
    if (t < nbs) partialscan[t] = lds[t] - v;
}

// writes per-row offs; also seeds per-bucket gcursor at bucket boundaries
__global__ void blockscan_kernel(const int* __restrict__ counts,
                                 const int* __restrict__ partialscan,
                                 int* __restrict__ offs, int* __restrict__ gcursor, int n) {
    __shared__ int lds[SCAN_THREADS];
    int t = threadIdx.x;
    int i0 = blockIdx.x * SCAN_CHUNK + t * 2;
    int c0 = (i0 < n) ? counts[i0] : 0;
    int c1 = (i0 + 1 < n) ? counts[i0 + 1] : 0;
    int ts = c0 + c1;
    lds[t] = ts;
    __syncthreads();
    for (int off = 1; off < SCAN_THREADS; off <<= 1) {
        int add = (t >= off) ? lds[t - off] : 0;
        __syncthreads();
        lds[t] += add;
        __syncthreads();
    }
    int excl = lds[t] - ts + partialscan[blockIdx.x];
    if (i0 < n) {
        offs[i0] = excl;
        if ((i0 & (RB - 1)) == 0) gcursor[i0 >> RB_SHIFT] = excl;  // i0 always even
    }
    if (i0 + 1 < n) offs[i0 + 1] = excl + c0;
}

// ---- block-aggregated partition into 64-row bucket regions ----
__global__ void partition_kernel(const int* __restrict__ rows, const int* __restrict__ cols,
                                 const float* __restrict__ vals, int* __restrict__ gcursor,
                                 int2* __restrict__ epk, int n_edges, int nb) {
    extern __shared__ int lds[];
    int* hist = lds;
    int* cur = lds + nb;
    int t = threadIdx.x;
    int e0 = blockIdx.x * SCH;
    int e1 = min(e0 + SCH, n_edges);

    for (int i = t; i < nb; i += blockDim.x) hist[i] = 0;
    __syncthreads();
    for (int e = e0 + t; e < e1; e += blockDim.x)
        atomicAdd(&hist[rows[e] >> RB_SHIFT], 1);
    __syncthreads();
    for (int i = t; i < nb; i += blockDim.x) {
        int c = hist[i];
        cur[i] = c ? atomicAdd(&gcursor[i], c) : 0;
    }
    __syncthreads();
    for (int e = e0 + t; e < e1; e += blockDim.x) {
        int r = rows[e];
        int b = r >> RB_SHIFT;
        int p = atomicAdd(&cur[b], 1);
        epk[p] = make_int2(cols[e] | ((r & (RB - 1)) << COL_BITS),
                           __float_as_int(vals[e]));
    }
}

// ---- in-place sort of each bucket segment into exact per-row CSR order ----
__global__ __launch_bounds__(256) void bucket_sort_kernel(
    const int* __restrict__ offs, const int* __restrict__ counts, int2* __restrict__ epk,
    int n_nodes) {
    __shared__ int2 buf[LDSCAP];  // 32 KB
    __shared__ int lcur[RB];
    int b = blockIdx.x;
    int row0 = b << RB_SHIFT;
    int rows = min(RB, n_nodes - row0);
    int s = offs[row0];
    int end = offs[row0 + rows - 1] + counts[row0 + rows - 1];
    int cnt = end - s;
    if (cnt > LDSCAP) return;  // rowacc filter path handles it
    int t = threadIdx.x;
    if (t < rows) lcur[t] = offs[row0 + t];
    __syncthreads();
    for (int i = t; i < cnt; i += 256) buf[i] = epk[s + i];
    __syncthreads();
    for (int i = t; i < cnt; i += 256) {
        int2 pk = buf[i];
        int rl = (int)((unsigned)pk.x >> COL_BITS);
        int p = atomicAdd(&lcur[rl], 1);
        epk[p] = pk;
    }
}

// ---- one wave per row: gather + accumulate + bias + coalesced write ----
__global__ void rowacc_kernel(const int* __restrict__ offs, const int* __restrict__ counts,
                              const int2* __restrict__ epk, const float* __restrict__ weight,
                              const float* __restrict__ bias, float* __restrict__ out,
                              int n_nodes) {
    int wid = (blockIdx.x * blockDim.x + threadIdx.x) >> 6;
    if (wid >= n_nodes) return;
    int lane = threadIdx.x & 63;
    const float2* w2 = (const float2*)weight;

    int b = wid >> RB_SHIFT;
    int row0 = b << RB_SHIFT;
    int rows = min(RB, n_nodes - row0);
    int bs = offs[row0];
    int bend = offs[row0 + rows - 1] + counts[row0 + rows - 1];

    float ax = 0.f, ay = 0.f;

    if (bend - bs > LDSCAP) {
        // bucket left unsorted: filter scan (rare / adversarial only)
        int rl_t = wid & (RB - 1);
        for (int e = bs; e < bend; ++e) {
            int2 pk = epk[e];
            if ((int)((unsigned)pk.x >> COL_BITS) == rl_t) {
                float2 w = w2[(size_t)(pk.x & COL_MASK) * 64 + lane];
                float v = __int_as_float(pk.y);
                ax += v * w.x;
                ay += v * w.y;
            }
        }
    } else {
        int e = offs[wid];
        int end = e + counts[wid];
        // 8-deep ILP
        for (; e + 8 <= end; e += 8) {
            int2 p0 = epk[e], p1 = epk[e + 1], p2 = epk[e + 2], p3 = epk[e + 3];
            int2 p4 = epk[e + 4], p5 = epk[e + 5], p6 = epk[e + 6], p7 = epk[e + 7];
            float2 w0 = w2[(size_t)(p0.x & COL_MASK) * 64 + lane];
            float2 w1 = w2[(size_t)(p1.x & COL_MASK) * 64 + lane];
            float2 w2_ = w2[(size_t)(p2.x & COL_MASK) * 64 + lane];
            float2 w3 = w2[(size_t)(p3.x & COL_MASK) * 64 + lane];
            float2 w4 = w2[(size_t)(p4.x & COL_MASK) * 64 + lane];
            float2 w5 = w2[(size_t)(p5.x & COL_MASK) * 64 + lane];
            float2 w6 = w2[(size_t)(p6.x & COL_MASK) * 64 + lane];
            float2 w7 = w2[(size_t)(p7.x & COL_MASK) * 64 + lane];
            ax += __int_as_float(p0.y) * w0.x + __int_as_float(p1.y) * w1.x +
                  __int_as_float(p2.y) * w2_.x + __int_as_float(p3.y) * w3.x +
                  __int_as_float(p4.y) * w4.x + __int_as_float(p5.y) * w5.x +
                  __int_as_float(p6.y) * w6.x + __int_as_float(p7.y) * w7.x;
            ay += __int_as_float(p0.y) * w0.y + __int_as_float(p1.y) * w1.y +
                  __int_as_float(p2.y) * w2_.y + __int_as_float(p3.y) * w3.y +
                  __int_as_float(p4.y) * w4.y + __int_as_float(p5.y) * w5.y +
                  __int_as_float(p6.y) * w6.y + __int_as_float(p7.y) * w7.y;
        }
        for (; e < end; ++e) {
            int2 pk = epk[e];
            float2 w = w2[(size_t)(pk.x & COL_MASK) * 64 + lane];
            float v = __int_as_float(pk.y);
            ax += v * w.x;
            ay += v * w.y;
        }
    }
    float2 bb = ((const float2*)bias)[lane];
    ((float2*)(out + (size_t)wid * F))[lane] = make_float2(ax + bb.x, ay + bb.y);
}

// ---------------- fallback: atomic path ----------------
__global__ void init_out_kernel(float* __restrict__ out, const float* __restrict__ bias,
                                int n_nodes) {
    const float4* b4 = (const float4*)bias;
    float4* o4 = (float4*)out;
    int total = n_nodes * (F / 4);
    for (int i = blockIdx.x * blockDim.x + threadIdx.x; i < total;
         i += gridDim.x * blockDim.x)
        o4[i] = b4[i & (F / 4 - 1)];
}

__global__ void edge_scatter_kernel(const int* __restrict__ rows,
                                    const int* __restrict__ cols,
                                    const float* __restrict__ vals,
                                    const float* __restrict__ weight,
                                    float* __restrict__ out, int n_edges) {
    int e = (blockIdx.x * blockDim.x + threadIdx.x) >> 6;
    if (e >= n_edges) return;
    int lane = threadIdx.x & 63;
    float2 w = ((const float2*)(weight + (size_t)cols[e] * F))[lane];
    float val = vals[e];
    float* o = out + (size_t)rows[e] * F + lane * 2;
    unsafeAtomicAdd(o, val * w.x);
    unsafeAtomicAdd(o + 1, val * w.y);
}

extern "C" void kernel_launch(void* const* d_in, const int* in_sizes, int n_in,
                              void* d_out, int out_size, void* d_ws, size_t ws_size,
                              hipStream_t stream) {
    const int*   rows   = (const int*)d_in[0];
    const int*   cols   = (const int*)d_in[1];
    const float* vals   = (const float*)d_in[2];
    const float* weight = (const float*)d_in[3];
    const float* bias   = (const float*)d_in[4];
    float* out = (float*)d_out;

    int n_edges = in_sizes[0];
    int n_nodes = out_size / F;
    int nb = (n_nodes + RB - 1) / RB;                      // buckets
    int nbs = (n_nodes + SCAN_CHUNK - 1) / SCAN_CHUNK;     // scan blocks

    size_t need = ((size_t)2 * n_nodes + nb + 2 * SCAN_THREADS + 2 * (size_t)n_edges) * 4;

    if (ws_size < need || nbs > SCAN_THREADS) {
        init_out_kernel<<<2048, 256, 0, stream>>>(out, bias, n_nodes);
        int grid = (n_edges + 3) / 4;
        edge_scatter_kernel<<<grid, 256, 0, stream>>>(rows, cols, vals, weight, out,
                                                      n_edges);
        return;
    }

    int* counts      = (int*)d_ws;
    int* offs        = counts + n_nodes;
    int* gcursor     = offs + n_nodes;
    int* partial     = gcursor + nb;
    int* partialscan = partial + SCAN_THREADS;
    int2* epk        = (int2*)(partialscan + SCAN_THREADS);

    hipMemsetAsync(counts, 0, (size_t)n_nodes * 4, stream);
    hist_kernel<<<2048, 256, 0, stream>>>(rows, counts, n_edges);
    blocksum_kernel<<<nbs, SCAN_THREADS, 0, stream>>>(counts, partial, n_nodes);
    scanpartial_kernel<<<1, SCAN_THREADS, 0, stream>>>(partial, partialscan, nbs);
    blockscan_kernel<<<nbs, SCAN_THREADS, 0, stream>>>(counts, partialscan, offs, gcursor,
                                                       n_nodes);
    int pgrid = (n_edges + SCH - 1) / SCH;
    partition_kernel<<<pgrid, 256, 2 * nb * 4, stream>>>(rows, cols, vals, gcursor, epk,
                                                         n_edges, nb);
    bucket_sort_kernel<<<nb, 256, 0, stream>>>(offs, counts, epk, n_nodes);

    int grid = (n_nodes + 3) / 4;  // 4 waves (rows) per 256-thread block
    rowacc_kernel<<<grid, 256, 0, stream>>>(offs, counts, epk, weight, bias, out, n_nodes);
}

// Round 5
// 402.030 us; speedup vs baseline: 6.0533x; 1.1258x over previous
//
#include <hip/hip_runtime.h>

#define F 128
#define RB 64
#define RB_SHIFT 6
#define SCH 16384
#define COL_BITS 17
#define COL_MASK 0x1FFFF
#define SCAN_CHUNK 512
#define SCAN_THREADS 256
#define LDSCAP 4096

// ---- per-row histogram ----
__global__ void hist_kernel(const int* __restrict__ rows, int* __restrict__ counts,
                            int n_edges) {
    int stride = gridDim.x * blockDim.x;
    for (int i = blockIdx.x * blockDim.x + threadIdx.x; i < n_edges; i += stride)
        atomicAdd(&counts[rows[i]], 1);
}

// ---- weight fp32 -> packed bf16 (2 per uint), RNE ----
__global__ void wcvt_kernel(const float4* __restrict__ w, uint2* __restrict__ wb,
                            int total4) {
    int stride = gridDim.x * blockDim.x;
    for (int i = blockIdx.x * blockDim.x + threadIdx.x; i < total4; i += stride) {
        float4 f = w[i];
        uint bx = __float_as_uint(f.x), by = __float_as_uint(f.y);
        uint bz = __float_as_uint(f.z), bw = __float_as_uint(f.w);
        uint rx = (bx + 0x7FFFu + ((bx >> 16) & 1u)) >> 16;
        uint ry = (by + 0x7FFFu + ((by >> 16) & 1u)) >> 16;
        uint rz = (bz + 0x7FFFu + ((bz >> 16) & 1u)) >> 16;
        uint rw = (bw + 0x7FFFu + ((bw >> 16) & 1u)) >> 16;
        wb[i] = make_uint2(rx | (ry << 16), rz | (rw << 16));
    }
}

// ---- 3-kernel exact scan over n_nodes row counts ----
__global__ void blocksum_kernel(const int* __restrict__ counts, int* __restrict__ partial,
                                int n) {
    __shared__ int lds[SCAN_THREADS];
    int t = threadIdx.x;
    int i0 = blockIdx.x * SCAN_CHUNK + t * 2;
    int s = 0;
    if (i0 < n) s += counts[i0];
    if (i0 + 1 < n) s += counts[i0 + 1];
    lds[t] = s;
    __syncthreads();
    for (int off = SCAN_THREADS / 2; off > 0; off >>= 1) {
        if (t < off) lds[t] += lds[t + off];
        __syncthreads();
    }
    if (t == 0) partial[blockIdx.x] = lds[0];
}

__global__ void scanpartial_kernel(const int* __restrict__ partial,
                                   int* __restrict__ partialscan, int nbs) {
    __shared__ int lds[SCAN_THREADS];
    int t = threadIdx.x;
    int v = (t < nbs) ? partial[t] : 0;
    lds[t] = v;
    __syncthreads();
    for (int off = 1; off < SCAN_THREADS; off <<= 1) {
        int add = (t >= off) ? lds[t - off] : 0;
        __syncthreads();
        lds[t] += add;
        __syncthreads();
    }
    if (t < nbs) partialscan[t] = lds[t] - v;
}

__global__ void blockscan_kernel(const int* __restrict__ counts,
                                 const int* __restrict__ partialscan,
                                 int* __restrict__ offs, int* __restrict__ gcursor, int n) {
    __shared__ int lds[SCAN_THREADS];
    int t = threadIdx.x;
    int i0 = blockIdx.x * SCAN_CHUNK + t * 2;
    int c0 = (i0 < n) ? counts[i0] : 0;
    int c1 = (i0 + 1 < n) ? counts[i0 + 1] : 0;
    int ts = c0 + c1;
    lds[t] = ts;
    __syncthreads();
    for (int off = 1; off < SCAN_THREADS; off <<= 1) {
        int add = (t >= off) ? lds[t - off] : 0;
        __syncthreads();
        lds[t] += add;
        __syncthreads();
    }
    int excl = lds[t] - ts + partialscan[blockIdx.x];
    if (i0 < n) {
        offs[i0] = excl;
        if ((i0 & (RB - 1)) == 0) gcursor[i0 >> RB_SHIFT] = excl;
    }
    if (i0 + 1 < n) offs[i0 + 1] = excl + c0;
}

// ---- block-aggregated partition into 64-row bucket regions ----
__global__ void partition_kernel(const int* __restrict__ rows, const int* __restrict__ cols,
                                 const float* __restrict__ vals, int* __restrict__ gcursor,
                                 int2* __restrict__ epk, int n_edges, int nb) {
    extern __shared__ int lds[];
    int* hist = lds;
    int* cur = lds + nb;
    int t = threadIdx.x;
    int e0 = blockIdx.x * SCH;
    int e1 = min(e0 + SCH, n_edges);

    for (int i = t; i < nb; i += blockDim.x) hist[i] = 0;
    __syncthreads();
    for (int e = e0 + t; e < e1; e += blockDim.x)
        atomicAdd(&hist[rows[e] >> RB_SHIFT], 1);
    __syncthreads();
    for (int i = t; i < nb; i += blockDim.x) {
        int c = hist[i];
        cur[i] = c ? atomicAdd(&gcursor[i], c) : 0;
    }
    __syncthreads();
    for (int e = e0 + t; e < e1; e += blockDim.x) {
        int r = rows[e];
        int b = r >> RB_SHIFT;
        int p = atomicAdd(&cur[b], 1);
        epk[p] = make_int2(cols[e] | ((r & (RB - 1)) << COL_BITS),
                           __float_as_int(vals[e]));
    }
}

// ---- in-place sort of each bucket segment into per-row CSR order ----
__global__ __launch_bounds__(256) void bucket_sort_kernel(
    const int* __restrict__ offs, const int* __restrict__ counts, int2* __restrict__ epk,
    int n_nodes) {
    __shared__ int2 buf[LDSCAP];
    __shared__ int lcur[RB];
    int b = blockIdx.x;
    int row0 = b << RB_SHIFT;
    int rows = min(RB, n_nodes - row0);
    int s = offs[row0];
    int end = offs[row0 + rows - 1] + counts[row0 + rows - 1];
    int cnt = end - s;
    if (cnt > LDSCAP) return;
    int t = threadIdx.x;
    if (t < rows) lcur[t] = offs[row0 + t];
    __syncthreads();
    for (int i = t; i < cnt; i += 256) buf[i] = epk[s + i];
    __syncthreads();
    for (int i = t; i < cnt; i += 256) {
        int2 pk = buf[i];
        int rl = (int)((unsigned)pk.x >> COL_BITS);
        int p = atomicAdd(&lcur[rl], 1);
        epk[p] = pk;
    }
}

// ---- one wave per row, bf16 weight gather (4 B/lane) ----
__global__ void rowacc_bf16_kernel(const int* __restrict__ offs,
                                   const int* __restrict__ counts,
                                   const int2* __restrict__ epk,
                                   const uint* __restrict__ wb,
                                   const float* __restrict__ bias, float* __restrict__ out,
                                   int n_nodes) {
    int wid = (blockIdx.x * blockDim.x + threadIdx.x) >> 6;
    if (wid >= n_nodes) return;
    int lane = threadIdx.x & 63;

    int b = wid >> RB_SHIFT;
    int row0 = b << RB_SHIFT;
    int rows = min(RB, n_nodes - row0);
    int bs = offs[row0];
    int bend = offs[row0 + rows - 1] + counts[row0 + rows - 1];

    float ax = 0.f, ay = 0.f;

    if (bend - bs > LDSCAP) {
        int rl_t = wid & (RB - 1);
        for (int e = bs; e < bend; ++e) {
            int2 pk = epk[e];
            if ((int)((unsigned)pk.x >> COL_BITS) == rl_t) {
                uint u = wb[(size_t)(pk.x & COL_MASK) * 64 + lane];
                float v = __int_as_float(pk.y);
                ax += v * __uint_as_float(u << 16);
                ay += v * __uint_as_float(u & 0xFFFF0000u);
            }
        }
    } else {
        int e = offs[wid];
        int end = e + counts[wid];
        for (; e + 8 <= end; e += 8) {
            int2 p0 = epk[e], p1 = epk[e + 1], p2 = epk[e + 2], p3 = epk[e + 3];
            int2 p4 = epk[e + 4], p5 = epk[e + 5], p6 = epk[e + 6], p7 = epk[e + 7];
            uint u0 = wb[(size_t)(p0.x & COL_MASK) * 64 + lane];
            uint u1 = wb[(size_t)(p1.x & COL_MASK) * 64 + lane];
            uint u2 = wb[(size_t)(p2.x & COL_MASK) * 64 + lane];
            uint u3 = wb[(size_t)(p3.x & COL_MASK) * 64 + lane];
            uint u4 = wb[(size_t)(p4.x & COL_MASK) * 64 + lane];
            uint u5 = wb[(size_t)(p5.x & COL_MASK) * 64 + lane];
            uint u6 = wb[(size_t)(p6.x & COL_MASK) * 64 + lane];
            uint u7 = wb[(size_t)(p7.x & COL_MASK) * 64 + lane];
            float v0 = __int_as_float(p0.y), v1 = __int_as_float(p1.y);
            float v2 = __int_as_float(p2.y), v3 = __int_as_float(p3.y);
            float v4 = __int_as_float(p4.y), v5 = __int_as_float(p5.y);
            float v6 = __int_as_float(p6.y), v7 = __int_as_float(p7.y);
            ax += v0 * __uint_as_float(u0 << 16) + v1 * __uint_as_float(u1 << 16) +
                  v2 * __uint_as_float(u2 << 16) + v3 * __uint_as_float(u3 << 16) +
                  v4 * __uint_as_float(u4 << 16) + v5 * __uint_as_float(u5 << 16) +
                  v6 * __uint_as_float(u6 << 16) + v7 * __uint_as_float(u7 << 16);
            ay += v0 * __uint_as_float(u0 & 0xFFFF0000u) +
                  v1 * __uint_as_float(u1 & 0xFFFF0000u) +
                  v2 * __uint_as_float(u2 & 0xFFFF0000u) +
                  v3 * __uint_as_float(u3 & 0xFFFF0000u) +
                  v4 * __uint_as_float(u4 & 0xFFFF0000u) +
                  v5 * __uint_as_float(u5 & 0xFFFF0000u) +
                  v6 * __uint_as_float(u6 & 0xFFFF0000u) +
                  v7 * __uint_as_float(u7 & 0xFFFF0000u);
        }
        for (; e < end; ++e) {
            int2 pk = epk[e];
            uint u = wb[(size_t)(pk.x & COL_MASK) * 64 + lane];
            float v = __int_as_float(pk.y);
            ax += v * __uint_as_float(u << 16);
            ay += v * __uint_as_float(u & 0xFFFF0000u);
        }
    }
    float2 bb = ((const float2*)bias)[lane];
    ((float2*)(out + (size_t)wid * F))[lane] = make_float2(ax + bb.x, ay + bb.y);
}

// ---- fp32 rowacc (used when ws can't fit bf16 weight copy) ----
__global__ void rowacc_kernel(const int* __restrict__ offs, const int* __restrict__ counts,
                              const int2* __restrict__ epk, const float* __restrict__ weight,
                              const float* __restrict__ bias, float* __restrict__ out,
                              int n_nodes) {
    int wid = (blockIdx.x * blockDim.x + threadIdx.x) >> 6;
    if (wid >= n_nodes) return;
    int lane = threadIdx.x & 63;
    const float2* w2 = (const float2*)weight;

    int b = wid >> RB_SHIFT;
    int row0 = b << RB_SHIFT;
    int rows = min(RB, n_nodes - row0);
    int bs = offs[row0];
    int bend = offs[row0 + rows - 1] + counts[row0 + rows - 1];

    float ax = 0.f, ay = 0.f;
    if (bend - bs > LDSCAP) {
        int rl_t = wid & (RB - 1);
        for (int e = bs; e < bend; ++e) {
            int2 pk = epk[e];
            if ((int)((unsigned)pk.x >> COL_BITS) == rl_t) {
                float2 w = w2[(size_t)(pk.x & COL_MASK) * 64 + lane];
                float v = __int_as_float(pk.y);
                ax += v * w.x;
                ay += v * w.y;
            }
        }
    } else {
        int e = offs[wid];
        int end = e + counts[wid];
        for (; e + 4 <= end; e += 4) {
            int2 p0 = epk[e], p1 = epk[e + 1], p2 = epk[e + 2], p3 = epk[e + 3];
            float2 w0 = w2[(size_t)(p0.x & COL_MASK) * 64 + lane];
            float2 w1 = w2[(size_t)(p1.x & COL_MASK) * 64 + lane];
            float2 w2_ = w2[(size_t)(p2.x & COL_MASK) * 64 + lane];
            float2 w3 = w2[(size_t)(p3.x & COL_MASK) * 64 + lane];
            ax += __int_as_float(p0.y) * w0.x + __int_as_float(p1.y) * w1.x +
                  __int_as_float(p2.y) * w2_.x + __int_as_float(p3.y) * w3.x;
            ay += __int_as_float(p0.y) * w0.y + __int_as_float(p1.y) * w1.y +
                  __int_as_float(p2.y) * w2_.y + __int_as_float(p3.y) * w3.y;
        }
        for (; e < end; ++e) {
            int2 pk = epk[e];
            float2 w = w2[(size_t)(pk.x & COL_MASK) * 64 + lane];
            float v = __int_as_float(pk.y);
            ax += v * w.x;
            ay += v * w.y;
        }
    }
    float2 bb = ((const float2*)bias)[lane];
    ((float2*)(out + (size_t)wid * F))[lane] = make_float2(ax + bb.x, ay + bb.y);
}

// ---------------- fallback: atomic path ----------------
__global__ void init_out_kernel(float* __restrict__ out, const float* __restrict__ bias,
                                int n_nodes) {
    const float4* b4 = (const float4*)bias;
    float4* o4 = (float4*)out;
    int total = n_nodes * (F / 4);
    for (int i = blockIdx.x * blockDim.x + threadIdx.x; i < total;
         i += gridDim.x * blockDim.x)
        o4[i] = b4[i & (F / 4 - 1)];
}

__global__ void edge_scatter_kernel(const int* __restrict__ rows,
                                    const int* __restrict__ cols,
                                    const float* __restrict__ vals,
                                    const float* __restrict__ weight,
                                    float* __restrict__ out, int n_edges) {
    int e = (blockIdx.x * blockDim.x + threadIdx.x) >> 6;
    if (e >= n_edges) return;
    int lane = threadIdx.x & 63;
    float2 w = ((const float2*)(weight + (size_t)cols[e] * F))[lane];
    float val = vals[e];
    float* o = out + (size_t)rows[e] * F + lane * 2;
    unsafeAtomicAdd(o, val * w.x);
    unsafeAtomicAdd(o + 1, val * w.y);
}

extern "C" void kernel_launch(void* const* d_in, const int* in_sizes, int n_in,
                              void* d_out, int out_size, void* d_ws, size_t ws_size,
                              hipStream_t stream) {
    const int*   rows   = (const int*)d_in[0];
    const int*   cols   = (const int*)d_in[1];
    const float* vals   = (const float*)d_in[2];
    const float* weight = (const float*)d_in[3];
    const float* bias   = (const float*)d_in[4];
    float* out = (float*)d_out;

    int n_edges = in_sizes[0];
    int n_nodes = out_size / F;
    int nb = (n_nodes + RB - 1) / RB;
    int nbs = (n_nodes + SCAN_CHUNK - 1) / SCAN_CHUNK;

    size_t need_base = ((size_t)2 * n_nodes + nb + 2 * SCAN_THREADS) * 4 +
                       (size_t)n_edges * 8;
    size_t need_bf16 = need_base + (size_t)n_nodes * F * 2;

    if (ws_size < need_base || nbs > SCAN_THREADS) {
        init_out_kernel<<<2048, 256, 0, stream>>>(out, bias, n_nodes);
        int grid = (n_edges + 3) / 4;
        edge_scatter_kernel<<<grid, 256, 0, stream>>>(rows, cols, vals, weight, out,
                                                      n_edges);
        return;
    }

    int* counts      = (int*)d_ws;
    int* offs        = counts + n_nodes;
    int* gcursor     = offs + n_nodes;
    int* partial     = gcursor + nb;
    int* partialscan = partial + SCAN_THREADS;
    int2* epk        = (int2*)(partialscan + SCAN_THREADS);
    uint* wb         = (uint*)(epk + n_edges);

    bool use_bf16 = (ws_size >= need_bf16);

    hipMemsetAsync(counts, 0, (size_t)n_nodes * 4, stream);
    hist_kernel<<<2048, 256, 0, stream>>>(rows, counts, n_edges);
    if (use_bf16)
        wcvt_kernel<<<2048, 256, 0, stream>>>((const float4*)weight, (uint2*)wb,
                                              n_nodes * (F / 4));
    blocksum_kernel<<<nbs, SCAN_THREADS, 0, stream>>>(counts, partial, n_nodes);
    scanpartial_kernel<<<1, SCAN_THREADS, 0, stream>>>(partial, partialscan, nbs);
    blockscan_kernel<<<nbs, SCAN_THREADS, 0, stream>>>(counts, partialscan, offs, gcursor,
                                                       n_nodes);
    int pgrid = (n_edges + SCH - 1) / SCH;
    partition_kernel<<<pgrid, 256, 2 * nb * 4, stream>>>(rows, cols, vals, gcursor, epk,
                                                         n_edges, nb);
    bucket_sort_kernel<<<nb, 256, 0, stream>>>(offs, counts, epk, n_nodes);

    int grid = (n_nodes + 3) / 4;
    if (use_bf16)
        rowacc_bf16_kernel<<<grid, 256, 0, stream>>>(offs, counts, epk, wb, bias, out,
                                                     n_nodes);
    else
        rowacc_kernel<<<grid, 256, 0, stream>>>(offs, counts, epk, weight, bias, out,
                                                n_nodes);
}

// Round 6
// 278.025 us; speedup vs baseline: 8.7533x; 1.4460x over previous
//
#include <hip/hip_runtime.h>

#define F 128
#define RB 64
#define RB_SHIFT 6
#define CAP 4096
#define SCH 16384
#define COL_BITS 17
#define COL_MASK 0x1FFFF

// ---- weight fp32 -> packed bf16 (2 per uint), RNE ----
__global__ void wcvt_kernel(const float4* __restrict__ w, uint2* __restrict__ wb,
                            int total4) {
    int stride = gridDim.x * blockDim.x;
    for (int i = blockIdx.x * blockDim.x + threadIdx.x; i < total4; i += stride) {
        float4 f = w[i];
        uint bx = __float_as_uint(f.x), by = __float_as_uint(f.y);
        uint bz = __float_as_uint(f.z), bw = __float_as_uint(f.w);
        uint rx = (bx + 0x7FFFu + ((bx >> 16) & 1u)) >> 16;
        uint ry = (by + 0x7FFFu + ((by >> 16) & 1u)) >> 16;
        uint rz = (bz + 0x7FFFu + ((bz >> 16) & 1u)) >> 16;
        uint rw = (bw + 0x7FFFu + ((bw >> 16) & 1u)) >> 16;
        wb[i] = make_uint2(rx | (ry << 16), rz | (rw << 16));
    }
}

// ---- per-bucket histogram (LDS-aggregated, nb counters) ----
__global__ void bhist_kernel(const int* __restrict__ rows, int* __restrict__ counts,
                             int n_edges, int nb) {
    extern __shared__ int h[];
    int t = threadIdx.x;
    for (int i = t; i < nb; i += blockDim.x) h[i] = 0;
    __syncthreads();
    int stride = gridDim.x * blockDim.x;
    for (int e = blockIdx.x * blockDim.x + t; e < n_edges; e += stride)
        atomicAdd(&h[rows[e] >> RB_SHIFT], 1);
    __syncthreads();
    for (int i = t; i < nb; i += blockDim.x) {
        int c = h[i];
        if (c) atomicAdd(&counts[i], c);
    }
}

// ---- single-block exclusive scan over nb bucket counts ----
__global__ void bscan_kernel(const int* __restrict__ counts, int* __restrict__ boffs,
                             int* __restrict__ gcursor, int nb) {
    __shared__ int lds[1024];
    int t = threadIdx.x;
    int per = (nb + 1023) / 1024;
    int base = t * per;
    int s = 0;
    for (int i = 0; i < per; i++)
        if (base + i < nb) s += counts[base + i];
    lds[t] = s;
    __syncthreads();
    for (int off = 1; off < 1024; off <<= 1) {
        int a = (t >= off) ? lds[t - off] : 0;
        __syncthreads();
        lds[t] += a;
        __syncthreads();
    }
    int excl = lds[t] - s;
    for (int i = 0; i < per; i++) {
        if (base + i < nb) {
            boffs[base + i] = excl;
            gcursor[base + i] = excl;
            excl += counts[base + i];
        }
    }
    if (t == 1023) boffs[nb] = lds[1023];
}

// ---- block-aggregated partition into 64-row bucket regions ----
__global__ void partition_kernel(const int* __restrict__ rows, const int* __restrict__ cols,
                                 const float* __restrict__ vals, int* __restrict__ gcursor,
                                 int2* __restrict__ epk, int n_edges, int nb) {
    extern __shared__ int lds[];
    int* hist = lds;
    int* cur = lds + nb;
    int t = threadIdx.x;
    int e0 = blockIdx.x * SCH;
    int e1 = min(e0 + SCH, n_edges);

    for (int i = t; i < nb; i += blockDim.x) hist[i] = 0;
    __syncthreads();
    for (int e = e0 + t; e < e1; e += blockDim.x)
        atomicAdd(&hist[rows[e] >> RB_SHIFT], 1);
    __syncthreads();
    for (int i = t; i < nb; i += blockDim.x) {
        int c = hist[i];
        cur[i] = c ? atomicAdd(&gcursor[i], c) : 0;
    }
    __syncthreads();
    for (int e = e0 + t; e < e1; e += blockDim.x) {
        int r = rows[e];
        int b = r >> RB_SHIFT;
        int p = atomicAdd(&cur[b], 1);
        epk[p] = make_int2(cols[e] | ((r & (RB - 1)) << COL_BITS),
                           __float_as_int(vals[e]));
    }
}

// ---- fused: LDS row-sort of bucket + per-row accumulate + bias + write ----
__global__ __launch_bounds__(512, 8) void sortacc_kernel(
    const int* __restrict__ boffs, const int2* __restrict__ epk,
    const uint* __restrict__ wb, const float* __restrict__ bias,
    float* __restrict__ out, int n_nodes) {
    __shared__ int2 buf[CAP];     // 32 KB
    __shared__ int hist[RB], lstart[RB], lcur[RB];
    int b = blockIdx.x;
    int s = boffs[b];
    int cnt = boffs[b + 1] - s;
    int row0 = b << RB_SHIFT;
    int t = threadIdx.x;
    int lane = t & 63, w = t >> 6;
    float2 bb = ((const float2*)bias)[lane];

    if (cnt <= CAP) {
        if (t < RB) hist[t] = 0;
        __syncthreads();
        int2 r0, r1, r2, r3, r4, r5, r6, r7;
#define LOADK(rk, k)                                                     \
        {                                                                \
            int i = t + (k)*512;                                         \
            if (i < cnt) {                                               \
                rk = epk[s + i];                                         \
                atomicAdd(&hist[(unsigned)rk.x >> COL_BITS], 1);         \
            }                                                            \
        }
        LOADK(r0, 0) LOADK(r1, 1) LOADK(r2, 2) LOADK(r3, 3)
        LOADK(r4, 4) LOADK(r5, 5) LOADK(r6, 6) LOADK(r7, 7)
#undef LOADK
        __syncthreads();
        if (t < RB) lstart[t] = hist[t];
        __syncthreads();
        for (int off = 1; off < RB; off <<= 1) {
            int a = 0;
            if (t < RB && t >= off) a = lstart[t - off];
            __syncthreads();
            if (t < RB) lstart[t] += a;
            __syncthreads();
        }
        if (t < RB) {
            int st = lstart[t] - hist[t];
            lstart[t] = st;
            lcur[t] = st;
        }
        __syncthreads();
#define SCATK(rk, k)                                                     \
        {                                                                \
            int i = t + (k)*512;                                         \
            if (i < cnt) {                                               \
                int p = atomicAdd(&lcur[(unsigned)rk.x >> COL_BITS], 1); \
                buf[p] = rk;                                             \
            }                                                            \
        }
        SCATK(r0, 0) SCATK(r1, 1) SCATK(r2, 2) SCATK(r3, 3)
        SCATK(r4, 4) SCATK(r5, 5) SCATK(r6, 6) SCATK(r7, 7)
#undef SCATK
        __syncthreads();

        // wave w accumulates rows w*8 .. w*8+7
        for (int j = 0; j < 8; j++) {
            int rl = w * 8 + j;
            int gr = row0 + rl;
            if (gr >= n_nodes) break;
            int e = lstart[rl];
            int end = e + hist[rl];
            float ax = 0.f, ay = 0.f;
            for (; e + 8 <= end; e += 8) {
                int2 p0 = buf[e], p1 = buf[e + 1], p2 = buf[e + 2], p3 = buf[e + 3];
                int2 p4 = buf[e + 4], p5 = buf[e + 5], p6 = buf[e + 6], p7 = buf[e + 7];
                uint u0 = wb[(size_t)(p0.x & COL_MASK) * 64 + lane];
                uint u1 = wb[(size_t)(p1.x & COL_MASK) * 64 + lane];
                uint u2 = wb[(size_t)(p2.x & COL_MASK) * 64 + lane];
                uint u3 = wb[(size_t)(p3.x & COL_MASK) * 64 + lane];
                uint u4 = wb[(size_t)(p4.x & COL_MASK) * 64 + lane];
                uint u5 = wb[(size_t)(p5.x & COL_MASK) * 64 + lane];
                uint u6 = wb[(size_t)(p6.x & COL_MASK) * 64 + lane];
                uint u7 = wb[(size_t)(p7.x & COL_MASK) * 64 + lane];
                float v0 = __int_as_float(p0.y), v1 = __int_as_float(p1.y);
                float v2 = __int_as_float(p2.y), v3 = __int_as_float(p3.y);
                float v4 = __int_as_float(p4.y), v5 = __int_as_float(p5.y);
                float v6 = __int_as_float(p6.y), v7 = __int_as_float(p7.y);
                ax += v0 * __uint_as_float(u0 << 16) + v1 * __uint_as_float(u1 << 16) +
                      v2 * __uint_as_float(u2 << 16) + v3 * __uint_as_float(u3 << 16) +
                      v4 * __uint_as_float(u4 << 16) + v5 * __uint_as_float(u5 << 16) +
                      v6 * __uint_as_float(u6 << 16) + v7 * __uint_as_float(u7 << 16);
                ay += v0 * __uint_as_float(u0 & 0xFFFF0000u) +
                      v1 * __uint_as_float(u1 & 0xFFFF0000u) +
                      v2 * __uint_as_float(u2 & 0xFFFF0000u) +
                      v3 * __uint_as_float(u3 & 0xFFFF0000u) +
                      v4 * __uint_as_float(u4 & 0xFFFF0000u) +
                      v5 * __uint_as_float(u5 & 0xFFFF0000u) +
                      v6 * __uint_as_float(u6 & 0xFFFF0000u) +
                      v7 * __uint_as_float(u7 & 0xFFFF0000u);
            }
            for (; e < end; ++e) {
                int2 pk = buf[e];
                uint u = wb[(size_t)(pk.x & COL_MASK) * 64 + lane];
                float v = __int_as_float(pk.y);
                ax += v * __uint_as_float(u << 16);
                ay += v * __uint_as_float(u & 0xFFFF0000u);
            }
            ((float2*)(out + (size_t)gr * F))[lane] = make_float2(ax + bb.x, ay + bb.y);
        }
    } else {
        // overflow bucket: filter scan from global (correct, slow, ~never taken)
        for (int j = 0; j < 8; j++) {
            int rl = w * 8 + j;
            int gr = row0 + rl;
            if (gr >= n_nodes) break;
            float ax = 0.f, ay = 0.f;
            for (int e = s; e < s + cnt; ++e) {
                int2 pk = epk[e];
                if ((int)((unsigned)pk.x >> COL_BITS) == rl) {
                    uint u = wb[(size_t)(pk.x & COL_MASK) * 64 + lane];
                    float v = __int_as_float(pk.y);
                    ax += v * __uint_as_float(u << 16);
                    ay += v * __uint_as_float(u & 0xFFFF0000u);
                }
            }
            ((float2*)(out + (size_t)gr * F))[lane] = make_float2(ax + bb.x, ay + bb.y);
        }
    }
}

// ---------------- fallback: atomic path ----------------
__global__ void init_out_kernel(float* __restrict__ out, const float* __restrict__ bias,
                                int n_nodes) {
    const float4* b4 = (const float4*)bias;
    float4* o4 = (float4*)out;
    int total = n_nodes * (F / 4);
    for (int i = blockIdx.x * blockDim.x + threadIdx.x; i < total;
         i += gridDim.x * blockDim.x)
        o4[i] = b4[i & (F / 4 - 1)];
}

__global__ void edge_scatter_kernel(const int* __restrict__ rows,
                                    const int* __restrict__ cols,
                                    const float* __restrict__ vals,
                                    const float* __restrict__ weight,
                                    float* __restrict__ out, int n_edges) {
    int e = (blockIdx.x * blockDim.x + threadIdx.x) >> 6;
    if (e >= n_edges) return;
    int lane = threadIdx.x & 63;
    float2 w = ((const float2*)(weight + (size_t)cols[e] * F))[lane];
    float val = vals[e];
    float* o = out + (size_t)rows[e] * F + lane * 2;
    unsafeAtomicAdd(o, val * w.x);
    unsafeAtomicAdd(o + 1, val * w.y);
}

extern "C" void kernel_launch(void* const* d_in, const int* in_sizes, int n_in,
                              void* d_out, int out_size, void* d_ws, size_t ws_size,
                              hipStream_t stream) {
    const int*   rows   = (const int*)d_in[0];
    const int*   cols   = (const int*)d_in[1];
    const float* vals   = (const float*)d_in[2];
    const float* weight = (const float*)d_in[3];
    const float* bias   = (const float*)d_in[4];
    float* out = (float*)d_out;

    int n_edges = in_sizes[0];
    int n_nodes = out_size / F;
    int nb = (n_nodes + RB - 1) / RB;

    // ws layout: counts[nb] | boffs[nb+1] | gcursor[nb] | (pad to 8B) | epk[E] | wb[N*64]
    size_t head_ints = ((size_t)3 * nb + 2) & ~(size_t)1;
    size_t need = head_ints * 4 + (size_t)n_edges * 8 + (size_t)n_nodes * F * 2;

    if (ws_size < need || n_nodes > (1 << COL_BITS)) {
        init_out_kernel<<<2048, 256, 0, stream>>>(out, bias, n_nodes);
        int grid = (n_edges + 3) / 4;
        edge_scatter_kernel<<<grid, 256, 0, stream>>>(rows, cols, vals, weight, out,
                                                      n_edges);
        return;
    }

    int* counts  = (int*)d_ws;
    int* boffs   = counts + nb;          // nb+1 entries
    int* gcursor = boffs + nb + 1;
    int2* epk    = (int2*)((int*)d_ws + head_ints);
    uint* wb     = (uint*)(epk + n_edges);

    hipMemsetAsync(counts, 0, (size_t)nb * 4, stream);
    wcvt_kernel<<<2048, 256, 0, stream>>>((const float4*)weight, (uint2*)wb,
                                          n_nodes * (F / 4));
    bhist_kernel<<<512, 256, nb * 4, stream>>>(rows, counts, n_edges, nb);
    bscan_kernel<<<1, 1024, 0, stream>>>(counts, boffs, gcursor, nb);
    int pgrid = (n_edges + SCH - 1) / SCH;
    partition_kernel<<<pgrid, 256, 2 * nb * 4, stream>>>(rows, cols, vals, gcursor, epk,
                                                         n_edges, nb);
    sortacc_kernel<<<nb, 512, 0, stream>>>(boffs, epk, wb, bias, out, n_nodes);
}

// Round 7
// 182.258 us; speedup vs baseline: 13.3527x; 1.5255x over previous
//
#include <hip/hip_runtime.h>

#define F 128
#define RB 64
#define RB_SHIFT 6
#define CAP 4096
#define SCH 16384
#define PT 1024
#define COL_BITS 17
#define COL_MASK 0x1FFFF
#define MAXNB 2048

// ---- fused: weight fp32 -> int8 (per-row scale) + per-bucket histogram ----
__global__ __launch_bounds__(256) void cvt_hist_kernel(
    const float2* __restrict__ w2, ushort* __restrict__ wq, float* __restrict__ scales,
    int n_nodes, const int* __restrict__ rows, int* __restrict__ counts, int n_edges,
    int nb, int cvt_blocks, int hist_blocks) {
    if ((int)blockIdx.x < cvt_blocks) {
        int row = blockIdx.x * 4 + (threadIdx.x >> 6);
        if (row >= n_nodes) return;
        int lane = threadIdx.x & 63;
        float2 f = w2[(size_t)row * 64 + lane];
        float m = fmaxf(fabsf(f.x), fabsf(f.y));
        for (int off = 32; off; off >>= 1) m = fmaxf(m, __shfl_xor(m, off));
        float inv = m > 0.f ? 127.f / m : 0.f;
        int q0 = (int)rintf(f.x * inv);
        int q1 = (int)rintf(f.y * inv);
        wq[(size_t)row * 64 + lane] = (ushort)((q0 & 0xFF) | ((q1 & 0xFF) << 8));
        if (lane == 0) scales[row] = m * (1.f / 127.f);
    } else {
        __shared__ int h[MAXNB];
        int t = threadIdx.x;
        for (int i = t; i < nb; i += blockDim.x) h[i] = 0;
        __syncthreads();
        int b = blockIdx.x - cvt_blocks;
        int stride = hist_blocks * blockDim.x;
        for (int e = b * blockDim.x + t; e < n_edges; e += stride)
            atomicAdd(&h[rows[e] >> RB_SHIFT], 1);
        __syncthreads();
        for (int i = t; i < nb; i += blockDim.x) {
            int c = h[i];
            if (c) atomicAdd(&counts[i], c);
        }
    }
}

// ---- single-block exclusive scan over nb bucket counts ----
__global__ void bscan_kernel(const int* __restrict__ counts, int* __restrict__ boffs,
                             int* __restrict__ gcursor, int nb) {
    __shared__ int lds[1024];
    int t = threadIdx.x;
    int per = (nb + 1023) / 1024;
    int base = t * per;
    int s = 0;
    for (int i = 0; i < per; i++)
        if (base + i < nb) s += counts[base + i];
    lds[t] = s;
    __syncthreads();
    for (int off = 1; off < 1024; off <<= 1) {
        int a = (t >= off) ? lds[t - off] : 0;
        __syncthreads();
        lds[t] += a;
        __syncthreads();
    }
    int excl = lds[t] - s;
    for (int i = 0; i < per; i++) {
        if (base + i < nb) {
            boffs[base + i] = excl;
            gcursor[base + i] = excl;
            excl += counts[base + i];
        }
    }
    if (t == 1023) boffs[nb] = lds[1023];
}

// ---- block-aggregated partition; folds scale[col] into val ----
__global__ __launch_bounds__(PT) void partition_kernel(
    const int* __restrict__ rows, const int* __restrict__ cols,
    const float* __restrict__ vals, const float* __restrict__ scales,
    int* __restrict__ gcursor, int2* __restrict__ epk, int n_edges, int nb) {
    extern __shared__ int lds[];
    int* hist = lds;
    int* cur = lds + nb;
    int t = threadIdx.x;
    int e0 = blockIdx.x * SCH;
    int e1 = min(e0 + SCH, n_edges);

    for (int i = t; i < nb; i += blockDim.x) hist[i] = 0;
    __syncthreads();
    for (int e = e0 + t; e < e1; e += blockDim.x)
        atomicAdd(&hist[rows[e] >> RB_SHIFT], 1);
    __syncthreads();
    for (int i = t; i < nb; i += blockDim.x) {
        int c = hist[i];
        cur[i] = c ? atomicAdd(&gcursor[i], c) : 0;
    }
    __syncthreads();
    for (int e = e0 + t; e < e1; e += blockDim.x) {
        int r = rows[e];
        int c = cols[e];
        int b = r >> RB_SHIFT;
        float v = vals[e] * scales[c];
        int p = atomicAdd(&cur[b], 1);
        epk[p] = make_int2(c | ((r & (RB - 1)) << COL_BITS), __float_as_int(v));
    }
}

// ---- fused: LDS row-sort of bucket + int8 gather accumulate + bias + write ----
__global__ __launch_bounds__(512, 8) void sortacc_kernel(
    const int* __restrict__ boffs, const int2* __restrict__ epk,
    const ushort* __restrict__ wq, const float* __restrict__ bias,
    float* __restrict__ out, int n_nodes) {
    __shared__ int2 buf[CAP];  // 32 KB
    __shared__ int hist[RB], lstart[RB], lcur[RB];
    int b = blockIdx.x;
    int s = boffs[b];
    int cnt = boffs[b + 1] - s;
    int row0 = b << RB_SHIFT;
    int t = threadIdx.x;
    int lane = t & 63, w = t >> 6;
    float2 bb = ((const float2*)bias)[lane];

#define DEQX(u) ((float)(int)(signed char)((u) & 0xFF))
#define DEQY(u) ((float)(int)(signed char)((u) >> 8))

    if (cnt <= CAP) {
        if (t < RB) hist[t] = 0;
        __syncthreads();
        int2 r0, r1, r2, r3, r4, r5, r6, r7;
#define LOADK(rk, k)                                                     \
        {                                                                \
            int i = t + (k)*512;                                         \
            if (i < cnt) {                                               \
                rk = epk[s + i];                                         \
                atomicAdd(&hist[(unsigned)rk.x >> COL_BITS], 1);         \
            }                                                            \
        }
        LOADK(r0, 0) LOADK(r1, 1) LOADK(r2, 2) LOADK(r3, 3)
        LOADK(r4, 4) LOADK(r5, 5) LOADK(r6, 6) LOADK(r7, 7)
#undef LOADK
        __syncthreads();
        if (t < RB) lstart[t] = hist[t];
        __syncthreads();
        for (int off = 1; off < RB; off <<= 1) {
            int a = 0;
            if (t < RB && t >= off) a = lstart[t - off];
            __syncthreads();
            if (t < RB) lstart[t] += a;
            __syncthreads();
        }
        if (t < RB) {
            int st = lstart[t] - hist[t];
            lstart[t] = st;
            lcur[t] = st;
        }
        __syncthreads();
#define SCATK(rk, k)                                                     \
        {                                                                \
            int i = t + (k)*512;                                         \
            if (i < cnt) {                                               \
                int p = atomicAdd(&lcur[(unsigned)rk.x >> COL_BITS], 1); \
                buf[p] = rk;                                             \
            }                                                            \
        }
        SCATK(r0, 0) SCATK(r1, 1) SCATK(r2, 2) SCATK(r3, 3)
        SCATK(r4, 4) SCATK(r5, 5) SCATK(r6, 6) SCATK(r7, 7)
#undef SCATK
        __syncthreads();

        // wave w accumulates rows w*8 .. w*8+7
        for (int j = 0; j < 8; j++) {
            int rl = w * 8 + j;
            int gr = row0 + rl;
            if (gr >= n_nodes) break;
            int e = lstart[rl];
            int end = e + hist[rl];
            float ax = 0.f, ay = 0.f;
            for (; e + 8 <= end; e += 8) {
                int2 p0 = buf[e], p1 = buf[e + 1], p2 = buf[e + 2], p3 = buf[e + 3];
                int2 p4 = buf[e + 4], p5 = buf[e + 5], p6 = buf[e + 6], p7 = buf[e + 7];
                uint u0 = wq[((size_t)(p0.x & COL_MASK) << 6) + lane];
                uint u1 = wq[((size_t)(p1.x & COL_MASK) << 6) + lane];
                uint u2 = wq[((size_t)(p2.x & COL_MASK) << 6) + lane];
                uint u3 = wq[((size_t)(p3.x & COL_MASK) << 6) + lane];
                uint u4 = wq[((size_t)(p4.x & COL_MASK) << 6) + lane];
                uint u5 = wq[((size_t)(p5.x & COL_MASK) << 6) + lane];
                uint u6 = wq[((size_t)(p6.x & COL_MASK) << 6) + lane];
                uint u7 = wq[((size_t)(p7.x & COL_MASK) << 6) + lane];
                float v0 = __int_as_float(p0.y), v1 = __int_as_float(p1.y);
                float v2 = __int_as_float(p2.y), v3 = __int_as_float(p3.y);
                float v4 = __int_as_float(p4.y), v5 = __int_as_float(p5.y);
                float v6 = __int_as_float(p6.y), v7 = __int_as_float(p7.y);
                ax += v0 * DEQX(u0) + v1 * DEQX(u1) + v2 * DEQX(u2) + v3 * DEQX(u3) +
                      v4 * DEQX(u4) + v5 * DEQX(u5) + v6 * DEQX(u6) + v7 * DEQX(u7);
                ay += v0 * DEQY(u0) + v1 * DEQY(u1) + v2 * DEQY(u2) + v3 * DEQY(u3) +
                      v4 * DEQY(u4) + v5 * DEQY(u5) + v6 * DEQY(u6) + v7 * DEQY(u7);
            }
            for (; e < end; ++e) {
                int2 pk = buf[e];
                uint u = wq[((size_t)(pk.x & COL_MASK) << 6) + lane];
                float v = __int_as_float(pk.y);
                ax += v * DEQX(u);
                ay += v * DEQY(u);
            }
            ((float2*)(out + (size_t)gr * F))[lane] = make_float2(ax + bb.x, ay + bb.y);
        }
    } else {
        // overflow bucket: filter scan from global (correct, slow, ~never taken)
        for (int j = 0; j < 8; j++) {
            int rl = w * 8 + j;
            int gr = row0 + rl;
            if (gr >= n_nodes) break;
            float ax = 0.f, ay = 0.f;
            for (int e = s; e < s + cnt; ++e) {
                int2 pk = epk[e];
                if ((int)((unsigned)pk.x >> COL_BITS) == rl) {
                    uint u = wq[((size_t)(pk.x & COL_MASK) << 6) + lane];
                    float v = __int_as_float(pk.y);
                    ax += v * DEQX(u);
                    ay += v * DEQY(u);
                }
            }
            ((float2*)(out + (size_t)gr * F))[lane] = make_float2(ax + bb.x, ay + bb.y);
        }
    }
#undef DEQX
#undef DEQY
}

// ---------------- fallback: atomic path (fp32, exact) ----------------
__global__ void init_out_kernel(float* __restrict__ out, const float* __restrict__ bias,
                                int n_nodes) {
    const float4* b4 = (const float4*)bias;
    float4* o4 = (float4*)out;
    int total = n_nodes * (F / 4);
    for (int i = blockIdx.x * blockDim.x + threadIdx.x; i < total;
         i += gridDim.x * blockDim.x)
        o4[i] = b4[i & (F / 4 - 1)];
}

__global__ void edge_scatter_kernel(const int* __restrict__ rows,
                                    const int* __restrict__ cols,
                                    const float* __restrict__ vals,
                                    const float* __restrict__ weight,
                                    float* __restrict__ out, int n_edges) {
    int e = (blockIdx.x * blockDim.x + threadIdx.x) >> 6;
    if (e >= n_edges) return;
    int lane = threadIdx.x & 63;
    float2 w = ((const float2*)(weight + (size_t)cols[e] * F))[lane];
    float val = vals[e];
    float* o = out + (size_t)rows[e] * F + lane * 2;
    unsafeAtomicAdd(o, val * w.x);
    unsafeAtomicAdd(o + 1, val * w.y);
}

extern "C" void kernel_launch(void* const* d_in, const int* in_sizes, int n_in,
                              void* d_out, int out_size, void* d_ws, size_t ws_size,
                              hipStream_t stream) {
    const int*   rows   = (const int*)d_in[0];
    const int*   cols   = (const int*)d_in[1];
    const float* vals   = (const float*)d_in[2];
    const float* weight = (const float*)d_in[3];
    const float* bias   = (const float*)d_in[4];
    float* out = (float*)d_out;

    int n_edges = in_sizes[0];
    int n_nodes = out_size / F;
    int nb = (n_nodes + RB - 1) / RB;

    // ws layout: counts[nb] | boffs[nb+1] | gcursor[nb] | pad8 | epk[E] | scales[N] | wq
    size_t head_ints = ((size_t)3 * nb + 2) & ~(size_t)1;
    size_t epk_off    = head_ints * 4;
    size_t scales_off = epk_off + (size_t)n_edges * 8;
    size_t wq_off     = (scales_off + (size_t)n_nodes * 4 + 255) & ~(size_t)255;
    size_t need       = wq_off + (size_t)n_nodes * F;

    if (ws_size < need || n_nodes > (1 << COL_BITS) || nb > MAXNB) {
        init_out_kernel<<<2048, 256, 0, stream>>>(out, bias, n_nodes);
        int grid = (n_edges + 3) / 4;
        edge_scatter_kernel<<<grid, 256, 0, stream>>>(rows, cols, vals, weight, out,
                                                      n_edges);
        return;
    }

    int* counts    = (int*)d_ws;
    int* boffs     = counts + nb;          // nb+1 entries
    int* gcursor   = boffs + nb + 1;
    int2* epk      = (int2*)((char*)d_ws + epk_off);
    float* scales  = (float*)((char*)d_ws + scales_off);
    ushort* wq     = (ushort*)((char*)d_ws + wq_off);

    hipMemsetAsync(counts, 0, (size_t)nb * 4, stream);
    int cvt_blocks = (n_nodes + 3) / 4;
    int hist_blocks = 512;
    cvt_hist_kernel<<<cvt_blocks + hist_blocks, 256, 0, stream>>>(
        (const float2*)weight, wq, scales, n_nodes, rows, counts, n_edges, nb,
        cvt_blocks, hist_blocks);
    bscan_kernel<<<1, 1024, 0, stream>>>(counts, boffs, gcursor, nb);
    int pgrid = (n_edges + SCH - 1) / SCH;
    partition_kernel<<<pgrid, PT, 2 * nb * 4, stream>>>(rows, cols, vals, scales, gcursor,
                                                        epk, n_edges, nb);
    sortacc_kernel<<<nb, 512, 0, stream>>>(boffs, epk, wq, bias, out, n_nodes);
}